// Round 4
// baseline (425.000 us; speedup 1.0000x reference)
//
#include <hip/hip_runtime.h>

// ---- problem constants ----
#define D_   1024
#define H_   16
#define T_   2048
#define B_   2
#define BT_  (B_*T_)       // 4096
#define NIN_ 3088          // 3D + H
#define NP_  3200          // padded to 25*128
#define CHUNK_ 64
#define NCH_  (T_/CHUNK_)  // 32 chunks
#define GN_INV (1.0f/131072.0f)  // 1/(K*T)

typedef unsigned short u16;
typedef __attribute__((ext_vector_type(8))) __bf16 bf16x8;
typedef __attribute__((ext_vector_type(4))) float  f32x4;

struct __align__(16) F4 { float x, y, z, w; };
struct __align__(8)  U4 { u16 x, y, z, w; };

__device__ inline u16 f2bf(float f) {
  union { float f; unsigned u; } q; q.f = f;
  unsigned r = q.u + 0x7FFFu + ((q.u >> 16) & 1u);   // RNE
  return (u16)(r >> 16);
}

__device__ inline void gl_lds16(const void* g, void* l) {
  __builtin_amdgcn_global_load_lds(
      (const __attribute__((address_space(1))) unsigned*)g,
      (__attribute__((address_space(3))) unsigned*)l, 16, 0, 0);
}

// ---------------- f32 -> bf16 converts ----------------
__global__ void cvt4(const float* __restrict__ in, u16* __restrict__ out, int n) {
  int i = (blockIdx.x * 256 + threadIdx.x) * 4;
  if (i >= n) return;
  F4 f = *reinterpret_cast<const F4*>(in + i);
  U4 u; u.x = f2bf(f.x); u.y = f2bf(f.y); u.z = f2bf(f.z); u.w = f2bf(f.w);
  *reinterpret_cast<U4*>(out + i) = u;
}

// W_in (3088x1024) -> bf16 padded to 3200 rows (zero rows 3088..3199)
__global__ void cvtpad(const float* __restrict__ in, u16* __restrict__ out) {
  int i = (blockIdx.x * 256 + threadIdx.x) * 4;   // < 3200*1024
  int row = i >> 10;
  U4 u; u.x = 0; u.y = 0; u.z = 0; u.w = 0;
  if (row < NIN_) {
    F4 f = *reinterpret_cast<const F4*>(in + i);
    u.x = f2bf(f.x); u.y = f2bf(f.y); u.z = f2bf(f.z); u.w = f2bf(f.w);
  }
  *reinterpret_cast<U4*>(out + i) = u;
}

// ---------------- bf16 GEMM: C[M,N] = A[M,K] * B[N,K]^T, f32 out ----------------
// 128x128 tile, BK=64, 4 waves (2x2 of 64x64), mfma_f32_16x16x32_bf16
__global__ __launch_bounds__(256, 2) void gemm_bt(
    const u16* __restrict__ A, const u16* __restrict__ Bm,
    float* __restrict__ C, int M, int N, int K) {
  __shared__ __align__(16) u16 As[128 * 64];
  __shared__ __align__(16) u16 Bs[128 * 64];
  const int tid  = threadIdx.x;
  const int lane = tid & 63;
  const int wid  = tid >> 6;
  const int tm = blockIdx.y * 128, tn = blockIdx.x * 128;
  const int wm = (wid >> 1) * 64,  wn = (wid & 1) * 64;
  const int krow = lane & 15;
  const int ksub = (lane >> 4) * 8;
  f32x4 acc[4][4] = {};

  for (int kt = 0; kt < K; kt += 64) {
#pragma unroll
    for (int i = 0; i < 4; ++i) {
      int e = i * 2048 + tid * 8;          // element idx in [128][64] tile
      int r = e >> 6, c = e & 63;
      gl_lds16(A  + (size_t)(tm + r) * K + kt + c, &As[e]);
      gl_lds16(Bm + (size_t)(tn + r) * K + kt + c, &Bs[e]);
    }
    __syncthreads();                        // drains vmcnt before ds_read
#pragma unroll
    for (int kk = 0; kk < 64; kk += 32) {
      bf16x8 af[4], bfr[4];
#pragma unroll
      for (int i = 0; i < 4; ++i)
        af[i] = *reinterpret_cast<const bf16x8*>(&As[(wm + i * 16 + krow) * 64 + kk + ksub]);
#pragma unroll
      for (int i = 0; i < 4; ++i)
        bfr[i] = *reinterpret_cast<const bf16x8*>(&Bs[(wn + i * 16 + krow) * 64 + kk + ksub]);
#pragma unroll
      for (int mi = 0; mi < 4; ++mi)
#pragma unroll
        for (int ni = 0; ni < 4; ++ni)
          acc[mi][ni] = __builtin_amdgcn_mfma_f32_16x16x32_bf16(af[mi], bfr[ni], acc[mi][ni], 0, 0, 0);
    }
    __syncthreads();
  }
  // C/D layout (m89-verified): col = lane&15, row = (lane>>4)*4 + j
  const int rb = tm + wm + (lane >> 4) * 4;
  const int cb = tn + wn + (lane & 15);
#pragma unroll
  for (int mi = 0; mi < 4; ++mi)
#pragma unroll
    for (int ni = 0; ni < 4; ++ni)
#pragma unroll
      for (int j = 0; j < 4; ++j)
        C[(size_t)(rb + mi * 16 + j) * N + cb + ni * 16] = acc[mi][ni][j];
}

// ---------------- pointwise: conv(k)+silu gate on v, decay-gate -> ld ----------------
// proj layout: [BT][3200]; cols: r[0,1024) v[1024,2048) k[2048,3072) w[3072,3088)
__global__ void post_kernel(const float* __restrict__ proj,
                            const float* __restrict__ conv_w,
                            const float* __restrict__ conv_b,
                            const float* __restrict__ decay,
                            float* __restrict__ vv, float* __restrict__ ld) {
  int idx = blockIdx.x * 256 + threadIdx.x;    // over BT*D
  int d  = idx & 1023;
  int bt = idx >> 10;
  int t  = bt & 2047, b = bt >> 11;
  const float* prow = proj + (size_t)bt * NP_;
  float v = prow[1024 + d];
  float kc = conv_b[d];
#pragma unroll
  for (int j = 0; j < 4; ++j) {                // taps t-6 .. t-3
    int tt = t - 6 + j;
    float kv = (tt >= 0) ? proj[(size_t)(bt - 6 + j) * NP_ + 2048 + d] : 0.f;
    kc = fmaf(kv, conv_w[d * 4 + j], kc);
  }
  float sil = kc / (1.f + __expf(-kc));
  int h = d >> 6, k = d & 63;
  vv[(((size_t)(b * H_ + h)) * T_ + t) * 64 + k] = v * sil * (1.f / 32.f);
  if (d < H_) {
    float wv = prow[3072 + d];
    float g  = 1.f / (1.f + __expf(-(decay[d] + wv)));
    ld[((size_t)(b * H_ + d)) * T_ + t] = -8.f * (1.f - g) - 0.1f;
  }
}

// ---------------- cumsum of ld over T per (b,h) ----------------
__global__ void cumsum_kernel(const float* __restrict__ ld, float* __restrict__ cs) {
  __shared__ float ss[256];
  int bh = blockIdx.x;
  const float* L = ld + (size_t)bh * T_;
  float* Co = cs + (size_t)bh * T_;
  int tid = threadIdx.x;                       // 256, 8 elems each
  float v[8]; float s = 0.f;
#pragma unroll
  for (int i = 0; i < 8; ++i) { v[i] = L[tid * 8 + i]; s += v[i]; }
  ss[tid] = s; __syncthreads();
  for (int off = 1; off < 256; off <<= 1) {
    float t = (tid >= off) ? ss[tid - off] : 0.f;
    __syncthreads();
    ss[tid] += t;
    __syncthreads();
  }
  float run = ss[tid] - s;                     // exclusive prefix
#pragma unroll
  for (int i = 0; i < 8; ++i) { run += v[i]; Co[tid * 8 + i] = run; }
}

// ---------------- phase A: chunk-local scan, in-place on vv ----------------
// grid: (b,h,c) = 2*16*32 blocks of 64 threads (one k each)
__global__ void scanA_kernel(float* __restrict__ vv, const float* __restrict__ ld,
                             const float* __restrict__ cs,
                             float* __restrict__ ye, float* __restrict__ Pc) {
  int bh = blockIdx.x >> 5, c = blockIdx.x & 31;
  int k = threadIdx.x;
  int t0 = c * CHUNK_;
  const float* Lr = ld + (size_t)bh * T_;
  float* V = vv + ((size_t)bh * T_ + t0) * 64 + k;
  float y = 0.f;
#pragma unroll 8
  for (int i = 0; i < CHUNK_; ++i) {
    float a = __expf(Lr[t0 + i]);
    float x = V[(size_t)i * 64];
    y = fmaf(a, y, x);                         // y = x + a*y_prev
    V[(size_t)i * 64] = y;
  }
  const float* Cr = cs + (size_t)bh * T_;
  float csm1 = t0 ? Cr[t0 - 1] : 0.f;
  ye[(size_t)blockIdx.x * 64 + k] = y;
  Pc[(size_t)blockIdx.x * 64 + k] = __expf(Cr[t0 + CHUNK_ - 1] - csm1);
}

// ---------------- cross-chunk combine (tiny) + zero GN accumulators ----------------
__global__ void comb_kernel(const float* __restrict__ ye, const float* __restrict__ Pc,
                            float* __restrict__ cin, float* __restrict__ sums) {
  int g = blockIdx.x * 256 + threadIdx.x;      // 2048 = (b,h,k)
  int bh = g >> 6, k = g & 63;
  float s = 0.f;
  for (int c = 0; c < NCH_; ++c) {
    size_t i = ((size_t)bh * NCH_ + c) * 64 + k;
    cin[i] = s;
    s = ye[i] + Pc[i] * s;
  }
  if (g < 64) sums[g] = 0.f;
}

// ---------------- phase C: add carry, out = silu(r)*y, GN stats ----------------
__global__ void applyC_kernel(float* __restrict__ y, const float* __restrict__ proj,
                              const float* __restrict__ cs, const float* __restrict__ cin,
                              float* __restrict__ sums) {
  int idx = blockIdx.x * 256 + threadIdx.x;    // (bh,t,k) linear
  int k  = idx & 63;
  int t  = (idx >> 6) & 2047;
  int bh = idx >> 17;                          // 256 threads share one bh
  int b = bh >> 4, h = bh & 15;
  int t0 = t & ~(CHUNK_ - 1);
  float csm1 = t0 ? cs[(size_t)bh * T_ + t0 - 1] : 0.f;
  float ci = cin[(((size_t)bh * NCH_) + (t >> 6)) * 64 + k];
  float yf = fmaf(__expf(cs[(size_t)bh * T_ + t] - csm1), ci, y[idx]);
  float r = proj[(size_t)(b * T_ + t) * NP_ + h * 64 + k];
  float o = yf * (r / (1.f + __expf(-r)));
  y[idx] = o;
  // block reduce sum / sumsq -> 2 atomics
  float s1 = o, s2 = o * o;
#pragma unroll
  for (int m = 32; m; m >>= 1) { s1 += __shfl_xor(s1, m); s2 += __shfl_xor(s2, m); }
  __shared__ float ps[8];
  int wid = threadIdx.x >> 6, lane = threadIdx.x & 63;
  if (lane == 0) { ps[wid] = s1; ps[4 + wid] = s2; }
  __syncthreads();
  if (threadIdx.x == 0) {
    atomicAdd(&sums[bh],      ps[0] + ps[1] + ps[2] + ps[3]);
    atomicAdd(&sums[32 + bh], ps[4] + ps[5] + ps[6] + ps[7]);
  }
}

// ---------------- phase D: normalize + bf16 cast to (b,t,d) ----------------
__global__ void applyD_kernel(const float* __restrict__ o, const float* __restrict__ sums,
                              const float* __restrict__ gn_w, const float* __restrict__ gn_b,
                              u16* __restrict__ on) {
  int idx = blockIdx.x * 256 + threadIdx.x;    // (bh,t,k) linear
  int k  = idx & 63;
  int t  = (idx >> 6) & 2047;
  int bh = idx >> 17;
  int b = bh >> 4, h = bh & 15;
  float mean = sums[bh] * GN_INV;
  float var  = sums[32 + bh] * GN_INV - mean * mean;
  float inv  = rsqrtf(var + 1e-5f);
  int d = h * 64 + k;
  float val = (o[idx] - mean) * inv * gn_w[d] + gn_b[d];
  on[(size_t)(b * T_ + t) * D_ + d] = f2bf(val);
}

// ---------------- launch ----------------
extern "C" void kernel_launch(void* const* d_in, const int* in_sizes, int n_in,
                              void* d_out, int out_size, void* d_ws, size_t ws_size,
                              hipStream_t stream) {
  const float* x      = (const float*)d_in[0];
  const float* W_in   = (const float*)d_in[1];
  const float* conv_w = (const float*)d_in[2];
  const float* conv_b = (const float*)d_in[3];
  const float* decay  = (const float*)d_in[4];
  const float* gn_w   = (const float*)d_in[5];
  const float* gn_b   = (const float*)d_in[6];
  const float* W_out  = (const float*)d_in[7];
  float* out = (float*)d_out;

  char* p = (char*)d_ws;
  auto alloc = [&](size_t bytes) { void* r = (void*)p; p += (bytes + 255) & ~(size_t)255; return r; };
  u16*  xb   = (u16*)alloc((size_t)BT_ * D_ * 2);   // also reused as `on` after GEMM1
  u16*  wb   = (u16*)alloc((size_t)NP_ * D_ * 2);
  u16*  wob  = (u16*)alloc((size_t)D_ * D_ * 2);
  float* proj = (float*)alloc((size_t)BT_ * NP_ * 4);
  float* vv   = (float*)alloc((size_t)BT_ * D_ * 4);
  float* ldb  = (float*)alloc((size_t)B_ * H_ * T_ * 4);
  float* csb  = (float*)alloc((size_t)B_ * H_ * T_ * 4);
  float* ye   = (float*)alloc((size_t)B_ * H_ * NCH_ * 64 * 4);
  float* Pc   = (float*)alloc((size_t)B_ * H_ * NCH_ * 64 * 4);
  float* cin  = (float*)alloc((size_t)B_ * H_ * NCH_ * 64 * 4);
  float* sums = (float*)alloc(64 * 4);
  u16*  on   = xb;   // alias: xb dead after GEMM1, on written in applyD

  // Fail-loud guard: if workspace is too small, do nothing (clean absmax
  // failure with valid timing) instead of corrupting memory / crashing.
  if ((size_t)(p - (char*)d_ws) > ws_size) return;

  hipLaunchKernelGGL(cvt4,   dim3(BT_ * D_ / 1024), dim3(256), 0, stream, x, xb, BT_ * D_);
  hipLaunchKernelGGL(cvtpad, dim3(NP_ * D_ / 1024), dim3(256), 0, stream, W_in, wb);
  hipLaunchKernelGGL(cvt4,   dim3(D_ * D_ / 1024),  dim3(256), 0, stream, W_out, wob, D_ * D_);
  hipLaunchKernelGGL(gemm_bt, dim3(NP_ / 128, BT_ / 128), dim3(256), 0, stream, xb, wb, proj, BT_, NP_, D_);
  hipLaunchKernelGGL(post_kernel,   dim3(BT_ * D_ / 256), dim3(256), 0, stream, proj, conv_w, conv_b, decay, vv, ldb);
  hipLaunchKernelGGL(cumsum_kernel, dim3(B_ * H_),        dim3(256), 0, stream, ldb, csb);
  hipLaunchKernelGGL(scanA_kernel,  dim3(B_ * H_ * NCH_), dim3(64),  0, stream, vv, ldb, csb, ye, Pc);
  hipLaunchKernelGGL(comb_kernel,   dim3(8),              dim3(256), 0, stream, ye, Pc, cin, sums);
  hipLaunchKernelGGL(applyC_kernel, dim3(BT_ * D_ / 256), dim3(256), 0, stream, vv, proj, csb, cin, sums);
  hipLaunchKernelGGL(applyD_kernel, dim3(BT_ * D_ / 256), dim3(256), 0, stream, vv, sums, gn_w, gn_b, on);
  hipLaunchKernelGGL(gemm_bt, dim3(D_ / 128, BT_ / 128), dim3(256), 0, stream, on, wob, out, BT_, D_, D_);
}

// Round 5
// 225.749 us; speedup vs baseline: 1.8826x; 1.8826x over previous
//
#include <hip/hip_runtime.h>

// ---- problem constants ----
#define D_   1024
#define H_   16
#define T_   2048
#define B_   2
#define BT_  (B_*T_)       // 4096
#define NIN_ 3088          // 3D + H
#define NP_  3200          // padded to 25*128
#define CHUNK_ 64
#define NCH_  (T_/CHUNK_)  // 32 chunks
#define GN_INV (1.0f/131072.0f)  // 1/(K*T)
#define NBLK_C (BT_ * D_ / 256)  // 16384 applyC blocks

typedef unsigned short u16;
typedef __attribute__((ext_vector_type(8))) __bf16 bf16x8;
typedef __attribute__((ext_vector_type(4))) float  f32x4;

struct __align__(16) F4 { float x, y, z, w; };
struct __align__(8)  U4 { u16 x, y, z, w; };

__device__ inline u16 f2bf(float f) {
  union { float f; unsigned u; } q; q.f = f;
  unsigned r = q.u + 0x7FFFu + ((q.u >> 16) & 1u);   // RNE
  return (u16)(r >> 16);
}

__device__ inline void gl_lds16(const void* g, void* l) {
  __builtin_amdgcn_global_load_lds(
      (const __attribute__((address_space(1))) unsigned*)g,
      (__attribute__((address_space(3))) unsigned*)l, 16, 0, 0);
}

// ---------------- f32 -> bf16 converts ----------------
__global__ void cvt4(const float* __restrict__ in, u16* __restrict__ out, int n) {
  int i = (blockIdx.x * 256 + threadIdx.x) * 4;
  if (i >= n) return;
  F4 f = *reinterpret_cast<const F4*>(in + i);
  U4 u; u.x = f2bf(f.x); u.y = f2bf(f.y); u.z = f2bf(f.z); u.w = f2bf(f.w);
  *reinterpret_cast<U4*>(out + i) = u;
}

// W_in (3088x1024) -> bf16 padded to 3200 rows (zero rows 3088..3199)
__global__ void cvtpad(const float* __restrict__ in, u16* __restrict__ out) {
  int i = (blockIdx.x * 256 + threadIdx.x) * 4;   // < 3200*1024
  int row = i >> 10;
  U4 u; u.x = 0; u.y = 0; u.z = 0; u.w = 0;
  if (row < NIN_) {
    F4 f = *reinterpret_cast<const F4*>(in + i);
    u.x = f2bf(f.x); u.y = f2bf(f.y); u.z = f2bf(f.z); u.w = f2bf(f.w);
  }
  *reinterpret_cast<U4*>(out + i) = u;
}

// ---------------- bf16 GEMM: C[M,N] = A[M,K] * B[N,K]^T, f32 out ----------------
// 128x128 tile, BK=64, 4 waves (2x2 of 64x64), mfma_f32_16x16x32_bf16
__global__ __launch_bounds__(256, 2) void gemm_bt(
    const u16* __restrict__ A, const u16* __restrict__ Bm,
    float* __restrict__ C, int M, int N, int K) {
  __shared__ __align__(16) u16 As[128 * 64];
  __shared__ __align__(16) u16 Bs[128 * 64];
  const int tid  = threadIdx.x;
  const int lane = tid & 63;
  const int wid  = tid >> 6;
  const int tm = blockIdx.y * 128, tn = blockIdx.x * 128;
  const int wm = (wid >> 1) * 64,  wn = (wid & 1) * 64;
  const int krow = lane & 15;
  const int ksub = (lane >> 4) * 8;
  f32x4 acc[4][4] = {};

  for (int kt = 0; kt < K; kt += 64) {
#pragma unroll
    for (int i = 0; i < 4; ++i) {
      int e = i * 2048 + tid * 8;          // element idx in [128][64] tile
      int r = e >> 6, c = e & 63;
      gl_lds16(A  + (size_t)(tm + r) * K + kt + c, &As[e]);
      gl_lds16(Bm + (size_t)(tn + r) * K + kt + c, &Bs[e]);
    }
    __syncthreads();                        // drains vmcnt before ds_read
#pragma unroll
    for (int kk = 0; kk < 64; kk += 32) {
      bf16x8 af[4], bfr[4];
#pragma unroll
      for (int i = 0; i < 4; ++i)
        af[i] = *reinterpret_cast<const bf16x8*>(&As[(wm + i * 16 + krow) * 64 + kk + ksub]);
#pragma unroll
      for (int i = 0; i < 4; ++i)
        bfr[i] = *reinterpret_cast<const bf16x8*>(&Bs[(wn + i * 16 + krow) * 64 + kk + ksub]);
#pragma unroll
      for (int mi = 0; mi < 4; ++mi)
#pragma unroll
        for (int ni = 0; ni < 4; ++ni)
          acc[mi][ni] = __builtin_amdgcn_mfma_f32_16x16x32_bf16(af[mi], bfr[ni], acc[mi][ni], 0, 0, 0);
    }
    __syncthreads();
  }
  // C/D layout (m89-verified): col = lane&15, row = (lane>>4)*4 + j
  const int rb = tm + wm + (lane >> 4) * 4;
  const int cb = tn + wn + (lane & 15);
#pragma unroll
  for (int mi = 0; mi < 4; ++mi)
#pragma unroll
    for (int ni = 0; ni < 4; ++ni)
#pragma unroll
      for (int j = 0; j < 4; ++j)
        C[(size_t)(rb + mi * 16 + j) * N + cb + ni * 16] = acc[mi][ni][j];
}

// ---------------- pointwise: conv(k)+silu gate on v, decay-gate -> ld ----------------
// proj layout: [BT][3200]; cols: r[0,1024) v[1024,2048) k[2048,3072) w[3072,3088)
__global__ void post_kernel(const float* __restrict__ proj,
                            const float* __restrict__ conv_w,
                            const float* __restrict__ conv_b,
                            const float* __restrict__ decay,
                            float* __restrict__ vv, float* __restrict__ ld) {
  int idx = blockIdx.x * 256 + threadIdx.x;    // over BT*D
  int d  = idx & 1023;
  int bt = idx >> 10;
  int t  = bt & 2047, b = bt >> 11;
  const float* prow = proj + (size_t)bt * NP_;
  float v = prow[1024 + d];
  float kc = conv_b[d];
#pragma unroll
  for (int j = 0; j < 4; ++j) {                // taps t-6 .. t-3
    int tt = t - 6 + j;
    float kv = (tt >= 0) ? proj[(size_t)(bt - 6 + j) * NP_ + 2048 + d] : 0.f;
    kc = fmaf(kv, conv_w[d * 4 + j], kc);
  }
  float sil = kc / (1.f + __expf(-kc));
  int h = d >> 6, k = d & 63;
  vv[(((size_t)(b * H_ + h)) * T_ + t) * 64 + k] = v * sil * (1.f / 32.f);
  if (d < H_) {
    float wv = prow[3072 + d];
    float g  = 1.f / (1.f + __expf(-(decay[d] + wv)));
    ld[((size_t)(b * H_ + d)) * T_ + t] = -8.f * (1.f - g) - 0.1f;
  }
}

// ---------------- cumsum of ld over T per (b,h) ----------------
__global__ void cumsum_kernel(const float* __restrict__ ld, float* __restrict__ cs) {
  __shared__ float ss[256];
  int bh = blockIdx.x;
  const float* L = ld + (size_t)bh * T_;
  float* Co = cs + (size_t)bh * T_;
  int tid = threadIdx.x;                       // 256, 8 elems each
  float v[8]; float s = 0.f;
#pragma unroll
  for (int i = 0; i < 8; ++i) { v[i] = L[tid * 8 + i]; s += v[i]; }
  ss[tid] = s; __syncthreads();
  for (int off = 1; off < 256; off <<= 1) {
    float t = (tid >= off) ? ss[tid - off] : 0.f;
    __syncthreads();
    ss[tid] += t;
    __syncthreads();
  }
  float run = ss[tid] - s;                     // exclusive prefix
#pragma unroll
  for (int i = 0; i < 8; ++i) { run += v[i]; Co[tid * 8 + i] = run; }
}

// ---------------- phase A: chunk-local scan, in-place on vv ----------------
// grid: (b,h,c) = 2*16*32 blocks of 64 threads (one k each)
__global__ void scanA_kernel(float* __restrict__ vv, const float* __restrict__ ld,
                             const float* __restrict__ cs,
                             float* __restrict__ ye, float* __restrict__ Pc) {
  int bh = blockIdx.x >> 5, c = blockIdx.x & 31;
  int k = threadIdx.x;
  int t0 = c * CHUNK_;
  const float* Lr = ld + (size_t)bh * T_;
  float* V = vv + ((size_t)bh * T_ + t0) * 64 + k;
  float y = 0.f;
#pragma unroll 8
  for (int i = 0; i < CHUNK_; ++i) {
    float a = __expf(Lr[t0 + i]);
    float x = V[(size_t)i * 64];
    y = fmaf(a, y, x);                         // y = x + a*y_prev
    V[(size_t)i * 64] = y;
  }
  const float* Cr = cs + (size_t)bh * T_;
  float csm1 = t0 ? Cr[t0 - 1] : 0.f;
  ye[(size_t)blockIdx.x * 64 + k] = y;
  Pc[(size_t)blockIdx.x * 64 + k] = __expf(Cr[t0 + CHUNK_ - 1] - csm1);
}

// ---------------- cross-chunk combine (tiny) ----------------
__global__ void comb_kernel(const float* __restrict__ ye, const float* __restrict__ Pc,
                            float* __restrict__ cin) {
  int g = blockIdx.x * 256 + threadIdx.x;      // 2048 = (b,h,k)
  int bh = g >> 6, k = g & 63;
  float s = 0.f;
  for (int c = 0; c < NCH_; ++c) {
    size_t i = ((size_t)bh * NCH_ + c) * 64 + k;
    cin[i] = s;
    s = ye[i] + Pc[i] * s;
  }
}

// ---------------- phase C: add carry, out = silu(r)*y, GN partials (no atomics) ----------------
__global__ void applyC_kernel(float* __restrict__ y, const float* __restrict__ proj,
                              const float* __restrict__ cs, const float* __restrict__ cin,
                              float* __restrict__ part) {
  int idx = blockIdx.x * 256 + threadIdx.x;    // (bh,t,k) linear
  int k  = idx & 63;
  int t  = (idx >> 6) & 2047;
  int bh = idx >> 17;                          // 256 threads share one bh
  int b = bh >> 4, h = bh & 15;
  int t0 = t & ~(CHUNK_ - 1);
  float csm1 = t0 ? cs[(size_t)bh * T_ + t0 - 1] : 0.f;
  float ci = cin[(((size_t)bh * NCH_) + (t >> 6)) * 64 + k];
  float yf = fmaf(__expf(cs[(size_t)bh * T_ + t] - csm1), ci, y[idx]);
  float r = proj[(size_t)(b * T_ + t) * NP_ + h * 64 + k];
  float o = yf * (r / (1.f + __expf(-r)));
  y[idx] = o;
  // block reduce sum / sumsq -> contention-free per-block partials
  float s1 = o, s2 = o * o;
#pragma unroll
  for (int m = 32; m; m >>= 1) { s1 += __shfl_xor(s1, m); s2 += __shfl_xor(s2, m); }
  __shared__ float ps[8];
  int wid = threadIdx.x >> 6, lane = threadIdx.x & 63;
  if (lane == 0) { ps[wid] = s1; ps[4 + wid] = s2; }
  __syncthreads();
  if (threadIdx.x == 0) {
    part[blockIdx.x]          = ps[0] + ps[1] + ps[2] + ps[3];
    part[NBLK_C + blockIdx.x] = ps[4] + ps[5] + ps[6] + ps[7];
  }
}

// ---------------- reduce partials -> sums[bh], sums[32+bh] ----------------
// applyC block b has bh = b>>9 (512 blocks per bh, contiguous)
__global__ void reduce_kernel(const float* __restrict__ part, float* __restrict__ sums) {
  int bh = blockIdx.x;                         // 32 blocks, 256 threads
  int t = threadIdx.x;
  int base = bh * 512;
  float s1 = part[base + t]           + part[base + 256 + t];
  float s2 = part[NBLK_C + base + t]  + part[NBLK_C + base + 256 + t];
#pragma unroll
  for (int m = 32; m; m >>= 1) { s1 += __shfl_xor(s1, m); s2 += __shfl_xor(s2, m); }
  __shared__ float ps[8];
  int wid = t >> 6, lane = t & 63;
  if (lane == 0) { ps[wid] = s1; ps[4 + wid] = s2; }
  __syncthreads();
  if (t == 0) {
    sums[bh]      = ps[0] + ps[1] + ps[2] + ps[3];
    sums[32 + bh] = ps[4] + ps[5] + ps[6] + ps[7];
  }
}

// ---------------- phase D: normalize + bf16 cast to (b,t,d) ----------------
__global__ void applyD_kernel(const float* __restrict__ o, const float* __restrict__ sums,
                              const float* __restrict__ gn_w, const float* __restrict__ gn_b,
                              u16* __restrict__ on) {
  int idx = blockIdx.x * 256 + threadIdx.x;    // (bh,t,k) linear
  int k  = idx & 63;
  int t  = (idx >> 6) & 2047;
  int bh = idx >> 17;
  int b = bh >> 4, h = bh & 15;
  float mean = sums[bh] * GN_INV;
  float var  = sums[32 + bh] * GN_INV - mean * mean;
  float inv  = rsqrtf(var + 1e-5f);
  int d = h * 64 + k;
  float val = (o[idx] - mean) * inv * gn_w[d] + gn_b[d];
  on[(size_t)(b * T_ + t) * D_ + d] = f2bf(val);
}

// ---------------- launch ----------------
extern "C" void kernel_launch(void* const* d_in, const int* in_sizes, int n_in,
                              void* d_out, int out_size, void* d_ws, size_t ws_size,
                              hipStream_t stream) {
  const float* x      = (const float*)d_in[0];
  const float* W_in   = (const float*)d_in[1];
  const float* conv_w = (const float*)d_in[2];
  const float* conv_b = (const float*)d_in[3];
  const float* decay  = (const float*)d_in[4];
  const float* gn_w   = (const float*)d_in[5];
  const float* gn_b   = (const float*)d_in[6];
  const float* W_out  = (const float*)d_in[7];
  float* out = (float*)d_out;

  char* p = (char*)d_ws;
  auto alloc = [&](size_t bytes) { void* r = (void*)p; p += (bytes + 255) & ~(size_t)255; return r; };
  u16*  xb   = (u16*)alloc((size_t)BT_ * D_ * 2);   // also reused as `on` after GEMM1
  u16*  wb   = (u16*)alloc((size_t)NP_ * D_ * 2);
  u16*  wob  = (u16*)alloc((size_t)D_ * D_ * 2);
  float* proj = (float*)alloc((size_t)BT_ * NP_ * 4);
  float* vv   = (float*)alloc((size_t)BT_ * D_ * 4);
  float* ldb  = (float*)alloc((size_t)B_ * H_ * T_ * 4);
  float* csb  = (float*)alloc((size_t)B_ * H_ * T_ * 4);
  float* ye   = (float*)alloc((size_t)B_ * H_ * NCH_ * 64 * 4);
  float* Pc   = (float*)alloc((size_t)B_ * H_ * NCH_ * 64 * 4);
  float* cin  = (float*)alloc((size_t)B_ * H_ * NCH_ * 64 * 4);
  float* part = (float*)alloc((size_t)2 * NBLK_C * 4);   // per-block GN partials
  float* sums = (float*)alloc(64 * 4);
  u16*  on   = xb;   // alias: xb dead after GEMM1, on written in applyD

  // Fail-loud guard: if workspace is too small, do nothing (clean absmax
  // failure with valid timing) instead of corrupting memory / crashing.
  if ((size_t)(p - (char*)d_ws) > ws_size) return;

  hipLaunchKernelGGL(cvt4,   dim3(BT_ * D_ / 1024), dim3(256), 0, stream, x, xb, BT_ * D_);
  hipLaunchKernelGGL(cvtpad, dim3(NP_ * D_ / 1024), dim3(256), 0, stream, W_in, wb);
  hipLaunchKernelGGL(cvt4,   dim3(D_ * D_ / 1024),  dim3(256), 0, stream, W_out, wob, D_ * D_);
  hipLaunchKernelGGL(gemm_bt, dim3(NP_ / 128, BT_ / 128), dim3(256), 0, stream, xb, wb, proj, BT_, NP_, D_);
  hipLaunchKernelGGL(post_kernel,   dim3(BT_ * D_ / 256), dim3(256), 0, stream, proj, conv_w, conv_b, decay, vv, ldb);
  hipLaunchKernelGGL(cumsum_kernel, dim3(B_ * H_),        dim3(256), 0, stream, ldb, csb);
  hipLaunchKernelGGL(scanA_kernel,  dim3(B_ * H_ * NCH_), dim3(64),  0, stream, vv, ldb, csb, ye, Pc);
  hipLaunchKernelGGL(comb_kernel,   dim3(8),              dim3(256), 0, stream, ye, Pc, cin);
  hipLaunchKernelGGL(applyC_kernel, dim3(NBLK_C),         dim3(256), 0, stream, vv, proj, csb, cin, part);
  hipLaunchKernelGGL(reduce_kernel, dim3(32),             dim3(256), 0, stream, part, sums);
  hipLaunchKernelGGL(applyD_kernel, dim3(BT_ * D_ / 256), dim3(256), 0, stream, vv, sums, gn_w, gn_b, on);
  hipLaunchKernelGGL(gemm_bt, dim3(D_ / 128, BT_ / 128), dim3(256), 0, stream, on, wob, out, BT_, D_, D_);
}

// Round 6
// 198.790 us; speedup vs baseline: 2.1379x; 1.1356x over previous
//
#include <hip/hip_runtime.h>

// ---- problem constants ----
#define D_   1024
#define H_   16
#define T_   2048
#define B_   2
#define BT_  (B_*T_)       // 4096
#define NIN_ 3088          // 3D + H
#define NP_  3200          // padded to 25*128
#define CHUNK_ 64
#define NCH_  (T_/CHUNK_)  // 32 chunks
#define GN_INV (1.0f/131072.0f)  // 1/(K*T)
#define NBLK_C (BT_ * D_ / 256)  // 16384 applyC blocks

typedef unsigned short u16;
typedef __attribute__((ext_vector_type(8))) __bf16 bf16x8;
typedef __attribute__((ext_vector_type(4))) float  f32x4;

struct __align__(16) F4 { float x, y, z, w; };
struct __align__(8)  U4 { u16 x, y, z, w; };

__device__ inline u16 f2bf(float f) {
  union { float f; unsigned u; } q; q.f = f;
  unsigned r = q.u + 0x7FFFu + ((q.u >> 16) & 1u);   // RNE
  return (u16)(r >> 16);
}

__device__ inline void gl_lds16(const void* g, void* l) {
  __builtin_amdgcn_global_load_lds(
      (const __attribute__((address_space(1))) unsigned*)g,
      (__attribute__((address_space(3))) unsigned*)l, 16, 0, 0);
}

// ---------------- fused f32 -> bf16 converts (x, W_in padded, W_out) ----------------
__global__ void cvt_all(const float* __restrict__ x, const float* __restrict__ W_in,
                        const float* __restrict__ W_out,
                        u16* __restrict__ xb, u16* __restrict__ wb, u16* __restrict__ wob) {
  const int nx = BT_ * D_ / 4, nw = NP_ * D_ / 4, no = D_ * D_ / 4;
  int q = blockIdx.x * 256 + threadIdx.x;
  if (q < nx) {
    int i = q * 4;
    F4 f = *reinterpret_cast<const F4*>(x + i);
    U4 u; u.x = f2bf(f.x); u.y = f2bf(f.y); u.z = f2bf(f.z); u.w = f2bf(f.w);
    *reinterpret_cast<U4*>(xb + i) = u;
  } else if (q < nx + nw) {
    int i = (q - nx) * 4;
    int row = i >> 10;
    U4 u; u.x = 0; u.y = 0; u.z = 0; u.w = 0;
    if (row < NIN_) {
      F4 f = *reinterpret_cast<const F4*>(W_in + i);
      u.x = f2bf(f.x); u.y = f2bf(f.y); u.z = f2bf(f.z); u.w = f2bf(f.w);
    }
    *reinterpret_cast<U4*>(wb + i) = u;
  } else if (q < nx + nw + no) {
    int i = (q - nx - nw) * 4;
    F4 f = *reinterpret_cast<const F4*>(W_out + i);
    U4 u; u.x = f2bf(f.x); u.y = f2bf(f.y); u.z = f2bf(f.z); u.w = f2bf(f.w);
    *reinterpret_cast<U4*>(wob + i) = u;
  }
}

// ---------------- bf16 GEMM: C[M,N] = A[M,K] * B[N,K]^T, f32 out ----------------
// 128x128 tile, BK=64, 4 waves (2x2 of 64x64), mfma_f32_16x16x32_bf16.
// LDS XOR-swizzle (rule 21): linear LDS dest for global_load_lds, source
// 16B-block pre-permuted by blk^(row&7); ds_read applies the same XOR.
// Kills the 16-lane same-bank conflict of the 128B-row-stride tile.
__global__ __launch_bounds__(256, 2) void gemm_bt(
    const u16* __restrict__ A, const u16* __restrict__ Bm,
    float* __restrict__ C, int M, int N, int K) {
  __shared__ __align__(16) u16 As[128 * 64];
  __shared__ __align__(16) u16 Bs[128 * 64];
  const int tid  = threadIdx.x;
  const int lane = tid & 63;
  const int wid  = tid >> 6;
  const int tm = blockIdx.y * 128, tn = blockIdx.x * 128;
  const int wm = (wid >> 1) * 64,  wn = (wid & 1) * 64;
  const int krow = lane & 15;
  const int ksub = (lane >> 4) * 8;
  f32x4 acc[4][4] = {};

  for (int kt = 0; kt < K; kt += 64) {
#pragma unroll
    for (int i = 0; i < 4; ++i) {
      int e = i * 2048 + tid * 8;          // element idx in [128][64] tile
      int r = e >> 6;
      int c = (((tid & 7) ^ (r & 7)) << 3); // pre-swizzled source column
      gl_lds16(A  + (size_t)(tm + r) * K + kt + c, &As[e]);
      gl_lds16(Bm + (size_t)(tn + r) * K + kt + c, &Bs[e]);
    }
    __syncthreads();                        // drains vmcnt before ds_read
#pragma unroll
    for (int kk = 0; kk < 64; kk += 32) {
      bf16x8 af[4], bfr[4];
#pragma unroll
      for (int i = 0; i < 4; ++i) {
        int row = wm + i * 16 + krow;
        int b = (((kk + ksub) >> 3) ^ (row & 7)) << 3;
        af[i] = *reinterpret_cast<const bf16x8*>(&As[row * 64 + b]);
      }
#pragma unroll
      for (int i = 0; i < 4; ++i) {
        int row = wn + i * 16 + krow;
        int b = (((kk + ksub) >> 3) ^ (row & 7)) << 3;
        bfr[i] = *reinterpret_cast<const bf16x8*>(&Bs[row * 64 + b]);
      }
#pragma unroll
      for (int mi = 0; mi < 4; ++mi)
#pragma unroll
        for (int ni = 0; ni < 4; ++ni)
          acc[mi][ni] = __builtin_amdgcn_mfma_f32_16x16x32_bf16(af[mi], bfr[ni], acc[mi][ni], 0, 0, 0);
    }
    __syncthreads();
  }
  // C/D layout (m89-verified): col = lane&15, row = (lane>>4)*4 + j
  const int rb = tm + wm + (lane >> 4) * 4;
  const int cb = tn + wn + (lane & 15);
#pragma unroll
  for (int mi = 0; mi < 4; ++mi)
#pragma unroll
    for (int ni = 0; ni < 4; ++ni)
#pragma unroll
      for (int j = 0; j < 4; ++j)
        C[(size_t)(rb + mi * 16 + j) * N + cb + ni * 16] = acc[mi][ni][j];
}

// ---------------- pointwise: conv(k)+silu gate on v, decay-gate -> ld ----------------
// proj layout: [BT][3200]; cols: r[0,1024) v[1024,2048) k[2048,3072) w[3072,3088)
__global__ void post_kernel(const float* __restrict__ proj,
                            const float* __restrict__ conv_w,
                            const float* __restrict__ conv_b,
                            const float* __restrict__ decay,
                            float* __restrict__ vv, float* __restrict__ ld) {
  int idx = blockIdx.x * 256 + threadIdx.x;    // over BT*D
  int d  = idx & 1023;
  int bt = idx >> 10;
  int t  = bt & 2047, b = bt >> 11;
  const float* prow = proj + (size_t)bt * NP_;
  float v = prow[1024 + d];
  float kc = conv_b[d];
#pragma unroll
  for (int j = 0; j < 4; ++j) {                // taps t-6 .. t-3
    int tt = t - 6 + j;
    float kv = (tt >= 0) ? proj[(size_t)(bt - 6 + j) * NP_ + 2048 + d] : 0.f;
    kc = fmaf(kv, conv_w[d * 4 + j], kc);
  }
  float sil = kc / (1.f + __expf(-kc));
  int h = d >> 6, k = d & 63;
  vv[(((size_t)(b * H_ + h)) * T_ + t) * 64 + k] = v * sil * (1.f / 32.f);
  if (d < H_) {
    float wv = prow[3072 + d];
    float g  = 1.f / (1.f + __expf(-(decay[d] + wv)));
    ld[((size_t)(b * H_ + d)) * T_ + t] = -8.f * (1.f - g) - 0.1f;
  }
}

// ---------------- phase A: chunk-local scan, in-place on vv ----------------
// grid: (b,h,c) = 2*16*32 blocks of 64 threads (one k each).
// Also emits pfx[bh][t] = exp(cs[t]-cs[t0-1]) (chunk-local decay prefix,
// running product of a) and Pc = full-chunk product. cumsum kernel gone.
__global__ void scanA_kernel(float* __restrict__ vv, const float* __restrict__ ld,
                             float* __restrict__ ye, float* __restrict__ Pc,
                             float* __restrict__ pfx) {
  int bh = blockIdx.x >> 5, c = blockIdx.x & 31;
  int k = threadIdx.x;
  int t0 = c * CHUNK_;
  const float* Lr = ld + (size_t)bh * T_ + t0;
  float* V = vv + ((size_t)bh * T_ + t0) * 64 + k;
  float y = 0.f, pf = 1.f, my_pf = 1.f;
#pragma unroll 8
  for (int i = 0; i < CHUNK_; ++i) {
    float a = __expf(Lr[i]);
    pf *= a;                                   // prefix product (uniform across lanes)
    float x = V[(size_t)i * 64];
    y = fmaf(a, y, x);                         // y = x + a*y_prev
    V[(size_t)i * 64] = y;
    if (i == k) my_pf = pf;                    // lane k keeps prefix at t0+k
  }
  pfx[(size_t)bh * T_ + t0 + k] = my_pf;       // coalesced
  ye[(size_t)blockIdx.x * 64 + k] = y;
  Pc[(size_t)blockIdx.x * 64 + k] = pf;
}

// ---------------- cross-chunk combine (tiny) ----------------
__global__ void comb_kernel(const float* __restrict__ ye, const float* __restrict__ Pc,
                            float* __restrict__ cin) {
  int g = blockIdx.x * 256 + threadIdx.x;      // 2048 = (b,h,k)
  int bh = g >> 6, k = g & 63;
  float s = 0.f;
  for (int c = 0; c < NCH_; ++c) {
    size_t i = ((size_t)bh * NCH_ + c) * 64 + k;
    cin[i] = s;
    s = ye[i] + Pc[i] * s;
  }
}

// ---------------- phase C: add carry, out = silu(r)*y, GN partials (no atomics) ----------------
__global__ void applyC_kernel(float* __restrict__ y, const float* __restrict__ proj,
                              const float* __restrict__ pfx, const float* __restrict__ cin,
                              float* __restrict__ part) {
  int idx = blockIdx.x * 256 + threadIdx.x;    // (bh,t,k) linear
  int k  = idx & 63;
  int t  = (idx >> 6) & 2047;
  int bh = idx >> 17;                          // 256 threads share one bh
  int b = bh >> 4, h = bh & 15;
  float ci = cin[(((size_t)bh * NCH_) + (t >> 6)) * 64 + k];
  float yf = fmaf(pfx[(size_t)bh * T_ + t], ci, y[idx]);
  float r = proj[(size_t)(b * T_ + t) * NP_ + h * 64 + k];
  float o = yf * (r / (1.f + __expf(-r)));
  y[idx] = o;
  // block reduce sum / sumsq -> contention-free per-block partials
  float s1 = o, s2 = o * o;
#pragma unroll
  for (int m = 32; m; m >>= 1) { s1 += __shfl_xor(s1, m); s2 += __shfl_xor(s2, m); }
  __shared__ float ps[8];
  int wid = threadIdx.x >> 6, lane = threadIdx.x & 63;
  if (lane == 0) { ps[wid] = s1; ps[4 + wid] = s2; }
  __syncthreads();
  if (threadIdx.x == 0) {
    part[blockIdx.x]          = ps[0] + ps[1] + ps[2] + ps[3];
    part[NBLK_C + blockIdx.x] = ps[4] + ps[5] + ps[6] + ps[7];
  }
}

// ---------------- reduce partials -> sums[bh], sums[32+bh] ----------------
// applyC block b has bh = b>>9 (512 blocks per bh, contiguous)
__global__ void reduce_kernel(const float* __restrict__ part, float* __restrict__ sums) {
  int bh = blockIdx.x;                         // 32 blocks, 256 threads
  int t = threadIdx.x;
  int base = bh * 512;
  float s1 = part[base + t]           + part[base + 256 + t];
  float s2 = part[NBLK_C + base + t]  + part[NBLK_C + base + 256 + t];
#pragma unroll
  for (int m = 32; m; m >>= 1) { s1 += __shfl_xor(s1, m); s2 += __shfl_xor(s2, m); }
  __shared__ float ps[8];
  int wid = t >> 6, lane = t & 63;
  if (lane == 0) { ps[wid] = s1; ps[4 + wid] = s2; }
  __syncthreads();
  if (t == 0) {
    sums[bh]      = ps[0] + ps[1] + ps[2] + ps[3];
    sums[32 + bh] = ps[4] + ps[5] + ps[6] + ps[7];
  }
}

// ---------------- phase D: normalize + bf16 cast to (b,t,d) ----------------
__global__ void applyD_kernel(const float* __restrict__ o, const float* __restrict__ sums,
                              const float* __restrict__ gn_w, const float* __restrict__ gn_b,
                              u16* __restrict__ on) {
  int idx = blockIdx.x * 256 + threadIdx.x;    // (bh,t,k) linear
  int k  = idx & 63;
  int t  = (idx >> 6) & 2047;
  int bh = idx >> 17;
  int b = bh >> 4, h = bh & 15;
  float mean = sums[bh] * GN_INV;
  float var  = sums[32 + bh] * GN_INV - mean * mean;
  float inv  = rsqrtf(var + 1e-5f);
  int d = h * 64 + k;
  float val = (o[idx] - mean) * inv * gn_w[d] + gn_b[d];
  on[(size_t)(b * T_ + t) * D_ + d] = f2bf(val);
}

// ---------------- launch ----------------
extern "C" void kernel_launch(void* const* d_in, const int* in_sizes, int n_in,
                              void* d_out, int out_size, void* d_ws, size_t ws_size,
                              hipStream_t stream) {
  const float* x      = (const float*)d_in[0];
  const float* W_in   = (const float*)d_in[1];
  const float* conv_w = (const float*)d_in[2];
  const float* conv_b = (const float*)d_in[3];
  const float* decay  = (const float*)d_in[4];
  const float* gn_w   = (const float*)d_in[5];
  const float* gn_b   = (const float*)d_in[6];
  const float* W_out  = (const float*)d_in[7];
  float* out = (float*)d_out;

  char* p = (char*)d_ws;
  auto alloc = [&](size_t bytes) { void* r = (void*)p; p += (bytes + 255) & ~(size_t)255; return r; };
  u16*  xb   = (u16*)alloc((size_t)BT_ * D_ * 2);   // also reused as `on` after GEMM1
  u16*  wb   = (u16*)alloc((size_t)NP_ * D_ * 2);
  u16*  wob  = (u16*)alloc((size_t)D_ * D_ * 2);
  float* proj = (float*)alloc((size_t)BT_ * NP_ * 4);
  float* vv   = (float*)alloc((size_t)BT_ * D_ * 4);
  float* ldb  = (float*)alloc((size_t)B_ * H_ * T_ * 4);
  float* pfx  = (float*)alloc((size_t)B_ * H_ * T_ * 4);
  float* ye   = (float*)alloc((size_t)B_ * H_ * NCH_ * 64 * 4);
  float* Pc   = (float*)alloc((size_t)B_ * H_ * NCH_ * 64 * 4);
  float* cin  = (float*)alloc((size_t)B_ * H_ * NCH_ * 64 * 4);
  float* part = (float*)alloc((size_t)2 * NBLK_C * 4);   // per-block GN partials
  float* sums = (float*)alloc(64 * 4);
  u16*  on   = xb;   // alias: xb dead after GEMM1, on written in applyD

  // Fail-loud guard: if workspace is too small, do nothing (clean absmax
  // failure with valid timing) instead of corrupting memory / crashing.
  if ((size_t)(p - (char*)d_ws) > ws_size) return;

  const int nq = (BT_ * D_ + NP_ * D_ + D_ * D_) / 4;   // fused cvt quads
  hipLaunchKernelGGL(cvt_all, dim3((nq + 255) / 256), dim3(256), 0, stream,
                     x, W_in, W_out, xb, wb, wob);
  hipLaunchKernelGGL(gemm_bt, dim3(NP_ / 128, BT_ / 128), dim3(256), 0, stream, xb, wb, proj, BT_, NP_, D_);
  hipLaunchKernelGGL(post_kernel,   dim3(BT_ * D_ / 256), dim3(256), 0, stream, proj, conv_w, conv_b, decay, vv, ldb);
  hipLaunchKernelGGL(scanA_kernel,  dim3(B_ * H_ * NCH_), dim3(64),  0, stream, vv, ldb, ye, Pc, pfx);
  hipLaunchKernelGGL(comb_kernel,   dim3(8),              dim3(256), 0, stream, ye, Pc, cin);
  hipLaunchKernelGGL(applyC_kernel, dim3(NBLK_C),         dim3(256), 0, stream, vv, proj, pfx, cin, part);
  hipLaunchKernelGGL(reduce_kernel, dim3(32),             dim3(256), 0, stream, part, sums);
  hipLaunchKernelGGL(applyD_kernel, dim3(BT_ * D_ / 256), dim3(256), 0, stream, vv, sums, gn_w, gn_b, on);
  hipLaunchKernelGGL(gemm_bt, dim3(D_ / 128, BT_ / 128), dim3(256), 0, stream, on, wob, out, BT_, D_, D_);
}